// Round 2
// baseline (94.507 us; speedup 1.0000x reference)
//
#include <hip/hip_runtime.h>
#include <math.h>

#define NFFT 1024
#define MPTS 512      // complex FFT size
#define NBINS 513
#define BATCH 8
#define NROWS 4000
#define FPB 8         // output rows per block

__global__ __launch_bounds__(256) void istft_kernel(
    const float* __restrict__ re, const float* __restrict__ im,
    float* __restrict__ out)
{
    __shared__ float ar[MPTS], ai[MPTS];
    __shared__ float br[MPTS], bi[MPTS];
    __shared__ float twr[MPTS], twi[MPTS];   // e^{+2pi i k/1024}, k=0..511
    __shared__ float prev[MPTS];
    __shared__ float x512r;

    const int tid = threadIdx.x;
    const int b   = blockIdx.y;
    const int t0  = blockIdx.x * FPB;

    // Twiddle table: e^{+2*pi*i*k/1024} for k = 0..511 (once per block)
    {
        const float w0 = 6.283185307179586476925f / 1024.0f;
        int k = tid;
        float s0, c0;
        sincosf(w0 * (float)k, &s0, &c0);
        twr[k] = c0; twi[k] = s0;
        k += 256;
        sincosf(w0 * (float)k, &s0, &c0);
        twr[k] = c0; twi[k] = s0;
    }
    prev[tid] = 0.0f;
    prev[tid + 256] = 0.0f;
    __syncthreads();

    const int tstart = (t0 == 0) ? 0 : (t0 - 1);   // priming frame for carry
    int tend = t0 + FPB; if (tend > NROWS) tend = NROWS;

    for (int t = tstart; t < tend; ++t) {
        // ---- load X[0..512] for frame (b,t) into br/bi (+ scalar bin 512)
        const size_t base = ((size_t)b * NROWS + (size_t)t) * NBINS;
        const float* rep = re + base;
        const float* imp = im + base;
        br[tid]       = rep[tid];       bi[tid]       = imp[tid];
        br[tid + 256] = rep[tid + 256]; bi[tid + 256] = imp[tid + 256];
        if (tid == 0) { x512r = rep[512]; }   // Im(X[512]) ignored (pocketfft c2r)
        __syncthreads();

        // ---- build Z[k] = Xe[k] + i * (e^{+2pi i k/1024} * Xo[k]) into ar/ai
        #pragma unroll
        for (int half = 0; half < 2; ++half) {
            const int k = tid + half * 256;
            float xr = br[k], xi = bi[k];
            float rc, ic;
            if (k == 0) {
                // pocketfft c2r ignores Im(X[0]) and Im(X[512])
                xi = 0.0f; rc = x512r; ic = 0.0f;
            } else {
                const int kk = 512 - k; rc = br[kk]; ic = -bi[kk];
            }
            const float er = 0.5f * (xr + rc), ei = 0.5f * (xi + ic);
            const float hr = 0.5f * (xr - rc), hi = 0.5f * (xi - ic);
            const float wr = twr[k], wi = twi[k];
            const float o_r = wr * hr - wi * hi;
            const float o_i = wr * hi + wi * hr;
            ar[k] = er - o_i;
            ai[k] = ei + o_r;
        }
        __syncthreads();

        // ---- 512-pt inverse complex FFT (unnormalized), Stockham radix-2
        float* sr = ar; float* si = ai;
        float* dr = br; float* di = bi;
        #pragma unroll
        for (int st = 0; st < 9; ++st) {
            const int s  = 1 << st;
            const int ps = tid & ~(s - 1);        // p * s
            const float a_r = sr[tid],       a_i = si[tid];
            const float b_r = sr[tid + 256], b_i = si[tid + 256];
            const int tw = 2 * ps;                // <= 510
            const float wr = twr[tw], wi = twi[tw];
            const int i0 = tid + ps;              // q + 2*s*p
            dr[i0] = a_r + b_r;
            di[i0] = a_i + b_i;
            const float fr = a_r - b_r, fi = a_i - b_i;
            dr[i0 + s] = wr * fr - wi * fi;
            di[i0 + s] = wr * fi + wi * fr;
            __syncthreads();
            float* tp;
            tp = sr; sr = dr; dr = tp;
            tp = si; si = di; di = tp;
        }
        // result (z[m], natural order) now in sr/si; x[2m]=Re z[m], x[2m+1]=Im z[m]

        // ---- overlap-add: out[t][j] = sc*x[j] + prev[j]; prev[j] = sc*x[512+j]
        const float sc = 1.0f / 1024.0f;          // 0.5 * (1/512)
        float* op = out + ((size_t)b * NROWS + (size_t)t) * 512;
        const bool emit = (t >= t0);
        #pragma unroll
        for (int half = 0; half < 2; ++half) {
            const int j = tid + half * 256;
            const int h = j >> 1;
            const float vfirst  = ((j & 1) ? si[h]       : sr[h])       * sc;
            const float vsecond = ((j & 1) ? si[256 + h] : sr[256 + h]) * sc;
            if (emit) op[j] = vfirst + prev[j];
            prev[j] = vsecond;                    // same thread owns prev[j]
        }
        __syncthreads();   // protect sr/si (== br/bi) before next frame's load
    }
}

extern "C" void kernel_launch(void* const* d_in, const int* in_sizes, int n_in,
                              void* d_out, int out_size, void* d_ws, size_t ws_size,
                              hipStream_t stream) {
    const float* re = (const float*)d_in[0];
    const float* im = (const float*)d_in[1];
    float* out = (float*)d_out;
    dim3 grid((NROWS + FPB - 1) / FPB, BATCH);
    istft_kernel<<<grid, 256, 0, stream>>>(re, im, out);
}

// Round 3
// 51.413 us; speedup vs baseline: 1.8382x; 1.8382x over previous
//
#include <hip/hip_runtime.h>
#include <math.h>

#define NBINS 513
#define NROWS 4000
#define BATCH 8
#define FPB   15        // output rows per block
#define NITER 4         // 4 groups x 4 iters = 16 frames (incl. 1 priming)

__device__ __forceinline__ void cmul(float& ar, float& ai, float br, float bi) {
    const float tr = ar * br - ai * bi;
    ai = ar * bi + ai * br;
    ar = tr;
}

// In-place inverse DFT-8 (omega = e^{+2pi i/8}) on 8 complex register values.
__device__ __forceinline__ void idft8(float* xr, float* xi) {
    const float S = 0.70710678118654752440f;
    float er[4], ei[4], orr[4], oi[4];
    #pragma unroll
    for (int j = 0; j < 4; ++j) {
        er[j]  = xr[j] + xr[j+4];  ei[j] = xi[j] + xi[j+4];
        orr[j] = xr[j] - xr[j+4];  oi[j] = xi[j] - xi[j+4];
    }
    // f[j] = o[j] * w8^j : w8^0=1, w8^1=S(1+i), w8^2=i, w8^3=S(-1+i)
    const float f1r = S * (orr[1] - oi[1]), f1i = S * (orr[1] + oi[1]);
    const float f2r = -oi[2],               f2i = orr[2];
    const float f3r = S * (-orr[3] - oi[3]), f3i = S * (orr[3] - oi[3]);
    {   // DFT4 (w4 = +i) over evens -> y0,y2,y4,y6
        const float eer = er[0]+er[2], eei = ei[0]+ei[2];
        const float eor = er[0]-er[2], eoi = ei[0]-ei[2];
        const float oer = er[1]+er[3], oei = ei[1]+ei[3];
        const float oor = er[1]-er[3], ooi = ei[1]-ei[3];
        xr[0] = eer + oer;  xi[0] = eei + oei;
        xr[2] = eor - ooi;  xi[2] = eoi + oor;
        xr[4] = eer - oer;  xi[4] = eei - oei;
        xr[6] = eor + ooi;  xi[6] = eoi - oor;
    }
    {   // DFT4 over f -> y1,y3,y5,y7
        const float eer = orr[0]+f2r, eei = oi[0]+f2i;
        const float eor = orr[0]-f2r, eoi = oi[0]-f2i;
        const float oer = f1r+f3r,    oei = f1i+f3i;
        const float oor = f1r-f3r,    ooi = f1i-f3i;
        xr[1] = eer + oer;  xi[1] = eei + oei;
        xr[3] = eor - ooi;  xi[3] = eoi + oor;
        xr[5] = eer - oer;  xi[5] = eei - oei;
        xr[7] = eor + ooi;  xi[7] = eoi - oor;
    }
}

__global__ __launch_bounds__(256) void istft_kernel(
    const float* __restrict__ re, const float* __restrict__ im,
    float* __restrict__ out)
{
    __shared__ float2 tw2[512];       // e^{+2pi i k/1024}, k=0..511
    __shared__ float2 ex2[4][512];    // per-group exchange buffer / halves

    const int tid = threadIdx.x;
    const int u   = tid & 63;         // lane within group (group == wave)
    const int g   = tid >> 6;
    const int b   = blockIdx.y;
    const int t0  = blockIdx.x * FPB;

    {   // twiddle table
        const float w0 = 6.283185307179586476925f / 1024.0f;
        float s, c;
        int k = tid;
        sincosf(w0 * (float)k, &s, &c); tw2[k] = make_float2(c, s);
        k += 256;
        sincosf(w0 * (float)k, &s, &c); tw2[k] = make_float2(c, s);
    }
    __syncthreads();

    const int k1 = u >> 3;            // stage-A coords (also m0B for stage B)
    const int k2 = u & 7;             // (also k2B)

    float2 cc[4];                     // OLA carry (meaningful in group 0 only)
    #pragma unroll
    for (int m = 0; m < 4; ++m) cc[m] = make_float2(0.f, 0.f);

    for (int it = 0; it < NITER; ++it) {
        const int t = t0 - 1 + it * 4 + g;

        // ---- pack: Z[u+64j] = Xe + i*w1024^k*Xo, scaled by 0.5/1024 ----
        float zr8[8], zi8[8];
        if (t >= 0 && t < NROWS) {
            const size_t base = ((size_t)b * NROWS + (size_t)t) * NBINS;
            const float* rp = re + base;
            const float* ip = im + base;
            const float F = 4.8828125e-4f;   // 0.5 * (1/1024)
            #pragma unroll
            for (int j = 0; j < 8; ++j) {
                const int k = u + 64 * j;
                float xr = rp[k], xi = ip[k];
                float rc, ic;
                if (k == 0) { xi = 0.f; rc = rp[512]; ic = 0.f; }
                else        { rc = rp[512 - k]; ic = -ip[512 - k]; }
                const float er = F * (xr + rc), ei = F * (xi + ic);
                const float hr = F * (xr - rc), hi = F * (xi - ic);
                const float2 w = tw2[k];
                const float o_r = w.x * hr - w.y * hi;
                const float o_i = w.x * hi + w.y * hr;
                zr8[j] = er - o_i;
                zi8[j] = ei + o_r;
            }
        } else {
            #pragma unroll
            for (int j = 0; j < 8; ++j) { zr8[j] = 0.f; zi8[j] = 0.f; }
        }

        // ---- stage A: IDFT8 over k0, twiddle e^{2pi i k1*m0/64} ----
        idft8(zr8, zi8);
        {
            const float2 w1 = tw2[16 * k1];
            float tr = w1.x, ti = w1.y;
            #pragma unroll
            for (int m0 = 1; m0 < 8; ++m0) {
                cmul(zr8[m0], zi8[m0], tr, ti);
                cmul(tr, ti, w1.x, w1.y);
            }
        }
        // ---- exchange 1 (XOR swizzle, conflict-free) ----
        #pragma unroll
        for (int m0 = 0; m0 < 8; ++m0) {
            const int a = 64 * m0 + 8 * ((k1 ^ m0) & 7) + k2;
            ex2[g][a] = make_float2(zr8[m0], zi8[m0]);
        }
        __syncthreads();                             // B1
        #pragma unroll
        for (int kk = 0; kk < 8; ++kk) {             // read A'[k2, kk, m0B=k1]
            const int a = 64 * k1 + 8 * ((kk ^ k1) & 7) + k2;
            const float2 v = ex2[g][a];
            zr8[kk] = v.x; zi8[kk] = v.y;
        }
        // ---- stage B: IDFT8 over k1, twiddle e^{2pi i k2*(m0B+8*m1)/512} ----
        idft8(zr8, zi8);
        {
            const float2 b0 = tw2[2 * k2 * k1];      // e^{2pi i k2*m0B/512}
            const float2 ws = tw2[16 * k2];          // e^{2pi i k2/64}
            float tr = b0.x, ti = b0.y;
            #pragma unroll
            for (int m1 = 0; m1 < 8; ++m1) {
                cmul(zr8[m1], zi8[m1], tr, ti);
                cmul(tr, ti, ws.x, ws.y);
            }
        }
        __syncthreads();                             // B2 (reads done)
        // ---- exchange 2 ----
        #pragma unroll
        for (int m1 = 0; m1 < 8; ++m1) {
            const int a = 64 * k2 + 8 * ((m1 ^ k2) & 7) + k1;
            ex2[g][a] = make_float2(zr8[m1], zi8[m1]);
        }
        __syncthreads();                             // B3
        #pragma unroll
        for (int kk = 0; kk < 8; ++kk) {             // read C'[kk, j=u]
            const int a = 64 * kk + 8 * ((k1 ^ kk) & 7) + k2;
            const float2 v = ex2[g][a];
            zr8[kk] = v.x; zi8[kk] = v.y;
        }
        // ---- stage C: IDFT8 over k2 -> z[u + 64*m2] ----
        idft8(zr8, zi8);
        __syncthreads();                             // B4 (reads done)

        // ---- store second half x[512..1023] as float2 pairs ----
        #pragma unroll
        for (int m = 0; m < 4; ++m)
            ex2[g][u + 64 * m] = make_float2(zr8[m + 4], zi8[m + 4]);
        __syncthreads();                             // B5

        // ---- emit out[t] = first_half + prev_half ----
        const bool emit = (t >= t0) && (t < NROWS);
        if (emit) {
            float2* orow = (float2*)(out + ((size_t)b * NROWS + (size_t)t) * 512);
            #pragma unroll
            for (int m = 0; m < 4; ++m) {
                float2 pv = (g == 0) ? cc[m] : ex2[g - 1][u + 64 * m];
                orow[u + 64 * m] = make_float2(zr8[m] + pv.x, zi8[m] + pv.y);
            }
        }
        if (g == 0) {   // refill carry from group 3's half (wave-local, ordered)
            #pragma unroll
            for (int m = 0; m < 4; ++m) cc[m] = ex2[3][u + 64 * m];
        }
        __syncthreads();                             // B6 (buffer reuse fence)
    }
}

extern "C" void kernel_launch(void* const* d_in, const int* in_sizes, int n_in,
                              void* d_out, int out_size, void* d_ws, size_t ws_size,
                              hipStream_t stream) {
    const float* re = (const float*)d_in[0];
    const float* im = (const float*)d_in[1];
    float* out = (float*)d_out;
    dim3 grid((NROWS + FPB - 1) / FPB, BATCH);
    istft_kernel<<<grid, 256, 0, stream>>>(re, im, out);
}

// Round 4
// 48.983 us; speedup vs baseline: 1.9294x; 1.0496x over previous
//
#include <hip/hip_runtime.h>
#include <math.h>

#define NBINS 513
#define NROWS 4000
#define BATCH 8
#define FPW   8                       // output rows per chain (one wave owns a chain)
#define CPB   4                       // chains (waves) per block
#define CHAINS_PER_BATCH (NROWS / FPW)   // 500

__device__ __forceinline__ void cmul(float& ar, float& ai, float br, float bi) {
    const float t = ar * br - ai * bi;
    ai = ar * bi + ai * br;
    ar = t;
}

// In-place inverse DFT-8 (omega = e^{+2pi i/8}) on 8 complex register values.
__device__ __forceinline__ void idft8(float* xr, float* xi) {
    const float S = 0.70710678118654752440f;
    float er[4], ei[4], orr[4], oi[4];
    #pragma unroll
    for (int j = 0; j < 4; ++j) {
        er[j]  = xr[j] + xr[j+4];  ei[j] = xi[j] + xi[j+4];
        orr[j] = xr[j] - xr[j+4];  oi[j] = xi[j] - xi[j+4];
    }
    const float f1r = S * (orr[1] - oi[1]), f1i = S * (orr[1] + oi[1]);
    const float f2r = -oi[2],               f2i = orr[2];
    const float f3r = S * (-orr[3] - oi[3]), f3i = S * (orr[3] - oi[3]);
    {   // DFT4 (w4 = +i) over evens -> y0,y2,y4,y6
        const float eer = er[0]+er[2], eei = ei[0]+ei[2];
        const float eor = er[0]-er[2], eoi = ei[0]-ei[2];
        const float oer = er[1]+er[3], oei = ei[1]+ei[3];
        const float oor = er[1]-er[3], ooi = ei[1]-ei[3];
        xr[0] = eer + oer;  xi[0] = eei + oei;
        xr[2] = eor - ooi;  xi[2] = eoi + oor;
        xr[4] = eer - oer;  xi[4] = eei - oei;
        xr[6] = eor + ooi;  xi[6] = eoi - oor;
    }
    {   // DFT4 over odds*w8 -> y1,y3,y5,y7
        const float eer = orr[0]+f2r, eei = oi[0]+f2i;
        const float eor = orr[0]-f2r, eoi = oi[0]-f2i;
        const float oer = f1r+f3r,    oei = f1i+f3i;
        const float oor = f1r-f3r,    ooi = f1i-f3i;
        xr[1] = eer + oer;  xi[1] = eei + oei;
        xr[3] = eor - ooi;  xi[3] = eoi + oor;
        xr[5] = eer - oer;  xi[5] = eei - oei;
        xr[7] = eor + ooi;  xi[7] = eoi - oor;
    }
}

__global__ __launch_bounds__(256) void istft_kernel(
    const float* __restrict__ re, const float* __restrict__ im,
    float* __restrict__ out)
{
    __shared__ float2 ex2[CPB][512];   // wave-private exchange regions

    const int tid = threadIdx.x;
    const int u   = tid & 63;
    const int g   = tid >> 6;
    const int b   = blockIdx.y;
    const int chain = blockIdx.x * CPB + g;       // 0..499
    const int t0  = chain * FPW;

    const int k1 = u >> 3;
    const int k2 = u & 7;

    // ---- loop-invariant per-thread twiddles (registers, no LDS table) ----
    const float w0 = 6.283185307179586476925f / 1024.0f;
    float2 twp[8];
    #pragma unroll
    for (int j = 0; j < 8; ++j) {
        float s, c; sincosf(w0 * (float)(u + 64 * j), &s, &c);
        twp[j] = make_float2(c, s);
    }
    float2 wA, wB0, wBs;
    {
        float s, c;
        sincosf(w0 * (float)(16 * k1), &s, &c);     wA  = make_float2(c, s);
        sincosf(w0 * (float)(2 * k2 * k1), &s, &c); wB0 = make_float2(c, s);
        sincosf(w0 * (float)(16 * k2), &s, &c);     wBs = make_float2(c, s);
    }

    float2 cc[4];                      // OLA carry — wave-private registers
    #pragma unroll
    for (int m = 0; m < 4; ++m) cc[m] = make_float2(0.f, 0.f);

    for (int t = t0 - 1; t < t0 + FPW; ++t) {
        // ---- pack: Z[u+64j] = Xe + i*w1024^k*Xo, scaled by 0.5/1024 ----
        float zr8[8], zi8[8];
        if (t >= 0) {
            const size_t base = ((size_t)b * NROWS + (size_t)t) * NBINS;
            const float* rp = re + base;
            const float* ip = im + base;
            const float F = 4.8828125e-4f;   // 0.5 * (1/1024)
            #pragma unroll
            for (int j = 0; j < 8; ++j) {
                const int k = u + 64 * j;
                float xr = rp[k], xi = ip[k];
                float rc, ic;
                if (k == 0) { xi = 0.f; rc = rp[512]; ic = 0.f; }  // pocketfft c2r
                else        { rc = rp[512 - k]; ic = -ip[512 - k]; }
                const float er = F * (xr + rc), ei = F * (xi + ic);
                const float hr = F * (xr - rc), hi = F * (xi - ic);
                const float o_r = twp[j].x * hr - twp[j].y * hi;
                const float o_i = twp[j].x * hi + twp[j].y * hr;
                zr8[j] = er - o_i;
                zi8[j] = ei + o_r;
            }
        } else {
            #pragma unroll
            for (int j = 0; j < 8; ++j) { zr8[j] = 0.f; zi8[j] = 0.f; }
        }

        // ---- stage A: IDFT8 over k0, twiddle w64^(k1*m0) ----
        idft8(zr8, zi8);
        {
            float tr = wA.x, ti = wA.y;
            #pragma unroll
            for (int m0 = 1; m0 < 8; ++m0) {
                cmul(zr8[m0], zi8[m0], tr, ti);
                cmul(tr, ti, wA.x, wA.y);
            }
        }
        // ---- exchange 1 (wave-internal, XOR swizzle, no barrier) ----
        #pragma unroll
        for (int m0 = 0; m0 < 8; ++m0)
            ex2[g][64 * m0 + 8 * ((k1 ^ m0) & 7) + k2] = make_float2(zr8[m0], zi8[m0]);
        #pragma unroll
        for (int kk = 0; kk < 8; ++kk) {
            const float2 v = ex2[g][64 * k1 + 8 * ((kk ^ k1) & 7) + k2];
            zr8[kk] = v.x; zi8[kk] = v.y;
        }

        // ---- stage B: IDFT8 over k1, twiddle w512^(k2*(m0B+8*m1)) ----
        idft8(zr8, zi8);
        {
            float tr = wB0.x, ti = wB0.y;
            #pragma unroll
            for (int m1 = 0; m1 < 8; ++m1) {
                cmul(zr8[m1], zi8[m1], tr, ti);
                cmul(tr, ti, wBs.x, wBs.y);
            }
        }
        // ---- exchange 2 (wave-internal) ----
        #pragma unroll
        for (int m1 = 0; m1 < 8; ++m1)
            ex2[g][64 * k2 + 8 * ((m1 ^ k2) & 7) + k1] = make_float2(zr8[m1], zi8[m1]);
        #pragma unroll
        for (int kk = 0; kk < 8; ++kk) {
            const float2 v = ex2[g][64 * kk + 8 * ((k1 ^ kk) & 7) + k2];
            zr8[kk] = v.x; zi8[kk] = v.y;
        }

        // ---- stage C: IDFT8 over k2 -> z[u + 64*m2] ----
        idft8(zr8, zi8);

        // ---- overlap-add, carry in registers (same thread owns both halves) ----
        if (t >= t0) {
            float2* orow = (float2*)(out + ((size_t)b * NROWS + (size_t)t) * 512);
            #pragma unroll
            for (int m = 0; m < 4; ++m)
                orow[u + 64 * m] = make_float2(zr8[m] + cc[m].x, zi8[m] + cc[m].y);
        }
        #pragma unroll
        for (int m = 0; m < 4; ++m) cc[m] = make_float2(zr8[m + 4], zi8[m + 4]);
    }
}

extern "C" void kernel_launch(void* const* d_in, const int* in_sizes, int n_in,
                              void* d_out, int out_size, void* d_ws, size_t ws_size,
                              hipStream_t stream) {
    const float* re = (const float*)d_in[0];
    const float* im = (const float*)d_in[1];
    float* out = (float*)d_out;
    dim3 grid(CHAINS_PER_BATCH / CPB, BATCH);
    istft_kernel<<<grid, 256, 0, stream>>>(re, im, out);
}